// Round 9
// baseline (647.117 us; speedup 1.0000x reference)
//
#include <hip/hip_runtime.h>
#include <hip/hip_bf16.h>
#include <math.h>

#define F_IN 128
#define HD   64    // H*D layer1
#define NH   8
#define DH   8
#define NC   7     // classes
#define NREP 8     // deg-histogram replicas (same-address atomic serialization /8)

__device__ __forceinline__ float lrelu(float e) { return fmaxf(e, 0.2f * e); }
__device__ __forceinline__ ushort f2bf(float f) {
    unsigned u = __float_as_uint(f);
    unsigned rounded = u + 0x7FFF + ((u >> 16) & 1);
    return (ushort)(rounded >> 16);
}

// ---------- K1 fused: gemm1 (bid%3==0) + hist (else) -------------------------
// gemm: R2-proven form (x-tile LDS broadcast b128, W1 half-cols in VGPRs).
// hist v3: REPLICATED histogram. deg_r[r][dst], r=(edge>>2)&7.  3.2M atomics
// onto 100K counters = avg 32 same-address RMWs; L2 serializes same-address
// atomics (~6cy each) => ~125us floor (matches the 150us plateau across
// different gemm bodies).  8 replicas cut collisions 32->4.  rank is within
// (r,dst); k_bsum computes per-dst exclusive prefix over replicas (pre).
__global__ __launch_bounds__(256) void k_gemm1h(
    const float* __restrict__ x, const float* __restrict__ W1,
    const float* __restrict__ att_src, const float* __restrict__ att_dst,
    ushort* __restrict__ h1b, float* __restrict__ a_src, float* __restrict__ a_dst,
    int N, int Npad, int GB,
    const int* __restrict__ dstArr, int* __restrict__ deg_r, int* __restrict__ rank,
    long E)
{
    __shared__ float sX[64 * F_IN];   // 32 KB  (64-row x tile)
    int t = threadIdx.x;
    int bid = blockIdx.x;

    if (bid % 3 != 0) {
        // ---- hist branch: 1024-edge groups, 4 edges/thread, int4 I/O ----
        long hb = (long)(bid / 3) * 2 + (bid % 3) - 1;    // [0, 2*GB)
        long gstride = (long)(2 * GB) * 1024;
        for (long base0 = hb * 1024; base0 < E; base0 += gstride) {
            long base = base0 + (long)t * 4;
            if (base >= E) continue;
            int r = (int)((base >> 2) & (NREP - 1));
            int* dg = deg_r + (size_t)r * Npad;
            if (base + 3 < E) {
                int4 d4 = *(const int4*)(dstArr + base);
                int r0_ = atomicAdd(&dg[d4.x], 1);
                int r1_ = atomicAdd(&dg[d4.y], 1);
                int r2_ = atomicAdd(&dg[d4.z], 1);
                int r3_ = atomicAdd(&dg[d4.w], 1);
                *(int4*)(rank + base) = make_int4(r0_, r1_, r2_, r3_);
            } else {
                for (long i = base; i < E; ++i)
                    rank[i] = atomicAdd(&dg[dstArr[i]], 1);
            }
        }
        return;
    }

    int gb = bid / 3;                                     // [0, GB)
    int lane = t & 63;
    int wave = t >> 6;

    // ---- batched, coalesced stage of the 64-row x tile ----
    {
        float4 xv[8];
        int r0b = gb * 64;
        #pragma unroll
        for (int i = 0; i < 8; ++i) {
            int ch = i * 256 + t;                 // 16B chunk id, 0..2047
            int rr = r0b + (ch >> 5);             // 32 chunks per 128-f row
            if (rr >= N) rr = N - 1;              // clamp tail (no OOB read)
            xv[i] = *(const float4*)(x + (size_t)rr * F_IN + ((ch & 31) << 2));
        }
        #pragma unroll
        for (int i = 0; i < 8; ++i) {
            int ch = i * 256 + t;
            *(float4*)(sX + ch * 4) = xv[i];
        }
    }
    float asv = att_src[lane];
    float adv = att_dst[lane];
    __syncthreads();

    int base = gb * 64 + wave * 16;

    #pragma unroll 1
    for (int it = 0; it < 2; ++it) {
        int r0 = base + it * 8;
        if (r0 >= N) break;
        int nr = N - r0; if (nr > 8) nr = 8;
        int lr = wave * 16 + it * 8;              // tile-local row base

        float acc[8];
        #pragma unroll
        for (int r = 0; r < 8; ++r) acc[r] = 0.f;

        #pragma unroll 1
        for (int kh = 0; kh < 2; ++kh) {
            // half-column of W1 into registers (coalesced; L1/L2-hot)
            float wreg[64];
            #pragma unroll
            for (int k = 0; k < 64; ++k)
                wreg[k] = W1[(kh * 64 + k) * HD + lane];

            const float* xb = sX + lr * F_IN + kh * 64;
            #pragma unroll
            for (int k4 = 0; k4 < 16; ++k4) {
                float4 xv[8];
                #pragma unroll
                for (int r = 0; r < 8; ++r)
                    xv[r] = *(const float4*)(xb + r * F_IN + k4 * 4);  // LDS b128 broadcast
                #pragma unroll
                for (int kk = 0; kk < 4; ++kk) {
                    float w = wreg[k4 * 4 + kk];
                    acc[0] += ((const float*)&xv[0])[kk] * w;
                    acc[1] += ((const float*)&xv[1])[kk] * w;
                    acc[2] += ((const float*)&xv[2])[kk] * w;
                    acc[3] += ((const float*)&xv[3])[kk] * w;
                    acc[4] += ((const float*)&xv[4])[kk] * w;
                    acc[5] += ((const float*)&xv[5])[kk] * w;
                    acc[6] += ((const float*)&xv[6])[kk] * w;
                    acc[7] += ((const float*)&xv[7])[kk] * w;
                }
            }
        }

        #pragma unroll
        for (int r = 0; r < 8; ++r) {
            if (r < nr) {
                int row = r0 + r;
                float a = acc[r];
                h1b[(size_t)row * HD + lane] = f2bf(a);
                float vs = a * asv;
                float vd = a * adv;
                #pragma unroll
                for (int o = 4; o > 0; o >>= 1) {
                    vs += __shfl_down(vs, o, 8);
                    vd += __shfl_down(vd, o, 8);
                }
                if ((lane & 7) == 0) {
                    int h = lane >> 3;
                    a_src[row * NH + h] = vs;
                    a_dst[row * NH + h] = vd;
                }
            }
        }
    }
}

// -------- K-bsum v2: replica prefix (pre), deg_total, block partial sum ------
__global__ __launch_bounds__(256) void k_bsum(
    const int* __restrict__ deg_r, int* __restrict__ pre,
    int* __restrict__ deg_total, int* __restrict__ bsum, int N, int Npad)
{
    __shared__ int s[256];
    int t = threadIdx.x;
    int i = blockIdx.x * 256 + t;
    int tot = 0;
    if (i < N) {
        #pragma unroll
        for (int r = 0; r < NREP; ++r) {
            int v = deg_r[(size_t)r * Npad + i];
            pre[(size_t)r * Npad + i] = tot;     // exclusive prefix over replicas
            tot += v;
        }
        deg_total[i] = tot;
    }
    s[t] = tot;
    __syncthreads();
    #pragma unroll
    for (int o = 128; o > 0; o >>= 1) {
        if (t < o) s[t] += s[t + o];
        __syncthreads();
    }
    if (t == 0) bsum[blockIdx.x] = s[0];
}

__global__ __launch_bounds__(512) void k_scan_bsum(
    const int* __restrict__ bsum, int* __restrict__ bexc, int NB)
{
    __shared__ int s[512];
    int t = threadIdx.x;
    s[t] = (t < NB) ? bsum[t] : 0;
    __syncthreads();
    for (int o = 1; o < 512; o <<= 1) {
        int v = (t >= o) ? s[t - o] : 0;
        __syncthreads();
        s[t] += v;
        __syncthreads();
    }
    if (t < NB) bexc[t] = (t == 0) ? 0 : s[t - 1];
}

__global__ __launch_bounds__(256) void k_rowptr(
    const int* __restrict__ deg, const int* __restrict__ bexc,
    int* __restrict__ rowptr, int N, int Etot)
{
    __shared__ int s[256];
    int t = threadIdx.x;
    int i = blockIdx.x * 256 + t;
    int v = (i < N) ? deg[i] : 0;
    s[t] = v;
    __syncthreads();
    for (int o = 1; o < 256; o <<= 1) {
        int u = (t >= o) ? s[t - o] : 0;
        __syncthreads();
        s[t] += u;
        __syncthreads();
    }
    if (i < N) rowptr[i] = bexc[blockIdx.x] + s[t] - v;  // exclusive
    if (i == 0) rowptr[N] = Etot;
}

// v3: 4 edges/thread, int4 loads; pos = rowptr[d] + pre[r][d] + rank
__global__ __launch_bounds__(256) void k_fill(
    const int* __restrict__ src, const int* __restrict__ dst,
    const int* __restrict__ rank, const int* __restrict__ rowptr,
    const int* __restrict__ pre, int* __restrict__ csr, int Npad, long E)
{
    long i4 = ((long)blockIdx.x * 256 + threadIdx.x) * 4;
    if (i4 >= E) return;
    const int* pr = pre + (size_t)((i4 >> 2) & (NREP - 1)) * Npad;
    if (i4 + 3 < E) {
        int4 d4 = *(const int4*)(dst + i4);
        int4 r4 = *(const int4*)(rank + i4);
        int4 s4 = *(const int4*)(src + i4);
        int p0 = rowptr[d4.x] + pr[d4.x];
        int p1 = rowptr[d4.y] + pr[d4.y];
        int p2 = rowptr[d4.z] + pr[d4.z];
        int p3 = rowptr[d4.w] + pr[d4.w];
        csr[p0 + r4.x] = s4.x;
        csr[p1 + r4.y] = s4.y;
        csr[p2 + r4.z] = s4.z;
        csr[p3 + r4.w] = s4.w;
    } else {
        for (long i = i4; i < E; ++i) {
            int d = dst[i];
            csr[rowptr[d] + pr[d] + rank[i]] = src[i];
        }
    }
}

// ---------------- K-gather1 v6: wave per dst, lane=(e,h), 3-stage pipeline ---
__global__ __launch_bounds__(256) void k_gather1(
    const int* __restrict__ rowptr, const int* __restrict__ csr,
    const ushort* __restrict__ h1b, const float* __restrict__ a_src,
    const float* __restrict__ a_dst, float* __restrict__ agg, int N)
{
    const uint* __restrict__ h1u = (const uint*)h1b;
    int wave = threadIdx.x >> 6, lane = threadIdx.x & 63;
    int d = blockIdx.x * 4 + wave;
    if (d >= N) return;
    int e = lane >> 3;           // edge slot
    int h = lane & 7;            // head; channels 8h..8h+7 = dwords 4h..4h+3

    float adst = a_dst[d * NH + h];
    float ws = __expf(lrelu(a_src[d * NH + h] + adst));   // self-loop weight
    float wsum = (e == 0) ? ws : 0.f;

    float ax0 = 0.f, ay0 = 0.f, ax1 = 0.f, ay1 = 0.f;
    float ax2 = 0.f, ay2 = 0.f, ax3 = 0.f, ay3 = 0.f;
    if (e == 0) {
        size_t b = (size_t)d * 32 + h * 4;
        uint u0 = h1u[b], u1 = h1u[b + 1], u2 = h1u[b + 2], u3 = h1u[b + 3];
        ax0 = ws * __uint_as_float(u0 << 16); ay0 = ws * __uint_as_float(u0 & 0xFFFF0000u);
        ax1 = ws * __uint_as_float(u1 << 16); ay1 = ws * __uint_as_float(u1 & 0xFFFF0000u);
        ax2 = ws * __uint_as_float(u2 << 16); ay2 = ws * __uint_as_float(u2 & 0xFFFF0000u);
        ax3 = ws * __uint_as_float(u3 << 16); ay3 = ws * __uint_as_float(u3 & 0xFFFF0000u);
    }

    int jb = rowptr[d], je = rowptr[d + 1];

    // ---- pipeline prologue ----
    int  idx0 = jb + e;
    bool v0   = idx0 < je;
    int  sl0  = v0 ? csr[idx0] : d;
    float as0 = a_src[sl0 * NH + h];
    size_t b0 = (size_t)sl0 * 32 + h * 4;
    uint u0 = h1u[b0], u1 = h1u[b0 + 1], u2 = h1u[b0 + 2], u3 = h1u[b0 + 3];

    int  idx1 = jb + 8 + e;
    bool v1   = idx1 < je;
    int  sl1  = v1 ? csr[idx1] : d;
    float as1 = a_src[sl1 * NH + h];

    int  idx2 = jb + 16 + e;
    bool v2   = idx2 < je;
    int  sl2  = v2 ? csr[idx2] : d;

    for (int j0 = jb; j0 < je; j0 += 8) {
        int  idx3 = j0 + 24 + e;
        bool v3   = idx3 < je;
        int  sl3  = v3 ? csr[idx3] : d;
        float as2 = a_src[sl2 * NH + h];
        size_t b1 = (size_t)sl1 * 32 + h * 4;
        uint n0 = h1u[b1], n1 = h1u[b1 + 1], n2 = h1u[b1 + 2], n3 = h1u[b1 + 3];

        float w = v0 ? __expf(lrelu(as0 + adst)) : 0.f;
        wsum += w;
        ax0 += w * __uint_as_float(u0 << 16); ay0 += w * __uint_as_float(u0 & 0xFFFF0000u);
        ax1 += w * __uint_as_float(u1 << 16); ay1 += w * __uint_as_float(u1 & 0xFFFF0000u);
        ax2 += w * __uint_as_float(u2 << 16); ay2 += w * __uint_as_float(u2 & 0xFFFF0000u);
        ax3 += w * __uint_as_float(u3 << 16); ay3 += w * __uint_as_float(u3 & 0xFFFF0000u);

        v0 = v1; as0 = as1; u0 = n0; u1 = n1; u2 = n2; u3 = n3;
        v1 = v2; sl1 = sl2; as1 = as2;
        v2 = v3; sl2 = sl3;
    }

    #pragma unroll
    for (int o = 8; o <= 32; o <<= 1) {
        wsum += __shfl_xor(wsum, o, 64);
        ax0 += __shfl_xor(ax0, o, 64); ay0 += __shfl_xor(ay0, o, 64);
        ax1 += __shfl_xor(ax1, o, 64); ay1 += __shfl_xor(ay1, o, 64);
        ax2 += __shfl_xor(ax2, o, 64); ay2 += __shfl_xor(ay2, o, 64);
        ax3 += __shfl_xor(ax3, o, 64); ay3 += __shfl_xor(ay3, o, 64);
    }
    if (e == 0) {
        float winv = 1.f / (wsum + 1e-16f);
        float* op = agg + (size_t)d * HD + h * 8;
        *(float4*)(op)     = make_float4(ax0 * winv, ay0 * winv, ax1 * winv, ay1 * winv);
        *(float4*)(op + 4) = make_float4(ax2 * winv, ay2 * winv, ax3 * winv, ay3 * winv);
    }
}

// ------- K4: emb = agg1+b1 (OUT0); x2 = elu(emb); h2p = x2@W2; a_*2 ----------
__global__ __launch_bounds__(256) void k_node2(
    const float* __restrict__ agg1, const float* __restrict__ b1,
    const float* __restrict__ W2, const float* __restrict__ att_s2,
    const float* __restrict__ att_d2, float* __restrict__ emb_out,
    float* __restrict__ h2p, float* __restrict__ a_src2, float* __restrict__ a_dst2,
    int N)
{
    __shared__ float sW[HD * NC];
    __shared__ float sb[HD];
    __shared__ float sas[NC], sad[NC];
    int t = threadIdx.x;
    for (int i = t; i < HD * NC; i += 256) sW[i] = W2[i];
    if (t < HD) sb[t] = b1[t];
    if (t < NC) { sas[t] = att_s2[t]; sad[t] = att_d2[t]; }
    __syncthreads();
    int n = blockIdx.x * 256 + t;
    if (n >= N) return;
    const float* ag = agg1 + (size_t)n * HD;
    float* eo = emb_out + (size_t)n * HD;
    float acc[NC];
    #pragma unroll
    for (int c = 0; c < NC; ++c) acc[c] = 0.f;
    #pragma unroll 8
    for (int k = 0; k < HD; ++k) {
        float v = ag[k] + sb[k];
        eo[k] = v;
        float xv = v > 0.f ? v : expm1f(v);   // jax.nn.elu
        #pragma unroll
        for (int c = 0; c < NC; ++c) acc[c] += xv * sW[k * NC + c];
    }
    float as = 0.f, ad = 0.f;
    float* hp = h2p + (size_t)n * 8;
    #pragma unroll
    for (int c = 0; c < NC; ++c) {
        hp[c] = acc[c];
        as += acc[c] * sas[c];
        ad += acc[c] * sad[c];
    }
    hp[7] = 0.f;
    a_src2[n] = as;
    a_dst2[n] = ad;
}

// ------- K-gather2 v2: WAVE per dst; depth-2 pipeline (as/hv one ahead) ------
__global__ __launch_bounds__(256) void k_gather2(
    const int* __restrict__ rowptr, const int* __restrict__ csr,
    const float* __restrict__ h2p, const float* __restrict__ a_src2,
    const float* __restrict__ a_dst2, const float* __restrict__ b2,
    float* __restrict__ out, int N)
{
    int t = threadIdx.x;
    int wave = t >> 6, lane = t & 63;
    int g = lane >> 3;           // edge slot 0..7
    int c = lane & 7;            // channel (7 = pad)
    int n = blockIdx.x * 4 + wave;
    if (n >= N) return;
    float ad = a_dst2[n];
    float w = __expf(lrelu(a_src2[n] + ad));   // self-loop
    float acc  = (g == 0) ? w * h2p[(size_t)n * 8 + c] : 0.f;
    float wsum = (g == 0) ? w : 0.f;
    int jb = rowptr[n], je = rowptr[n + 1];

    int  idx0 = jb + g;
    bool v0   = idx0 < je;
    int  s0   = v0 ? csr[idx0] : n;
    float as0 = a_src2[s0];
    float hv0 = h2p[(size_t)s0 * 8 + c];

    int  idx1 = jb + 8 + g;
    bool v1   = idx1 < je;
    int  s1   = v1 ? csr[idx1] : n;

    for (int j = jb; j < je; j += 8) {
        int  idx2 = j + 16 + g;
        bool v2   = idx2 < je;
        int  s2   = v2 ? csr[idx2] : n;
        float as1 = a_src2[s1];
        float hv1 = h2p[(size_t)s1 * 8 + c];
        float ww = v0 ? __expf(lrelu(as0 + ad)) : 0.f;
        acc += ww * hv0;
        wsum += ww;
        v0 = v1; as0 = as1; hv0 = hv1;
        v1 = v2; s1 = s2;
    }
    #pragma unroll
    for (int o = 32; o >= 8; o >>= 1) {
        acc  += __shfl_xor(acc, o, 64);
        wsum += __shfl_xor(wsum, o, 64);
    }
    float l = (c < NC) ? (acc / (wsum + 1e-16f) + b2[c]) : -1e30f;
    float m = l;
    #pragma unroll
    for (int o = 4; o > 0; o >>= 1) m = fmaxf(m, __shfl_xor(m, o, 8));
    float ex = (c < NC) ? __expf(l - m) : 0.f;
    float s8 = ex;
    #pragma unroll
    for (int o = 4; o > 0; o >>= 1) s8 += __shfl_xor(s8, o, 8);
    if (g == 0 && c < NC) out[(size_t)n * NC + c] = l - m - logf(s8);
}

extern "C" void kernel_launch(void* const* d_in, const int* in_sizes, int n_in,
                              void* d_out, int out_size, void* d_ws, size_t ws_size,
                              hipStream_t stream)
{
    const float* x       = (const float*)d_in[0];
    const int*   ei      = (const int*)d_in[1];
    const float* W1      = (const float*)d_in[2];
    const float* att_s1  = (const float*)d_in[3];
    const float* att_d1  = (const float*)d_in[4];
    const float* b1      = (const float*)d_in[5];
    const float* W2      = (const float*)d_in[6];
    const float* att_s2  = (const float*)d_in[7];
    const float* att_d2  = (const float*)d_in[8];
    const float* b2      = (const float*)d_in[9];

    const int  N = in_sizes[0] / F_IN;
    const long E = (long)in_sizes[1] / 2;
    const int* src = ei;
    const int* dst = ei + E;

    const int Npad  = (N + 3) & ~3;
    const int Np1p  = (N + 4) & ~3;
    const long Epad = (E + 3) & ~3;

    // ---- workspace layout ----
    int* deg_total = (int*)d_ws;              // Npad  (written by k_bsum)
    int* rowptr = deg_total + Npad;           // N+1
    int* bexc   = rowptr + Np1p;              // 512
    int* bsum   = bexc + 512;                 // 512
    int* csr    = bsum + 512;                 // E
    ushort* h1b   = (ushort*)(csr + Epad);    // Npad*64 bf16
    float* a_src1 = (float*)(h1b + (size_t)Npad * HD); // N*8
    float* a_dst1 = a_src1 + (size_t)N * NH;  // N*8
    float* agg1   = a_dst1 + (size_t)N * NH;  // N*64
    float* h2p    = agg1 + (size_t)N * HD;    // N*8 (padded NC->8)
    float* a_src2 = h2p + (size_t)N * 8;      // Npad
    float* a_dst2 = a_src2 + Npad;            // Npad
    float* wsend  = a_dst2 + Npad;
    // Aliases (lifetimes disjoint):
    //  deg_r[NREP][Npad] @ h2p block (h2p/a_src2/a_dst2 = N*8+2*Npad >= 8*Npad;
    //    deg_r dead after k_bsum, h2p first written in k_node2)
    //  rank[E]           @ agg1[0..Epad)          (dead after k_fill)
    //  pre[NREP][Npad]   @ agg1[Epad..Epad+8Npad) (dead after k_fill;
    //    Epad + 8*Npad = 3.2M + 0.8M <= N*HD = 6.4M)
    int* deg_r = (int*)h2p;
    int* rank  = (int*)agg1;
    int* pre   = (int*)agg1 + Epad;

    hipMemsetAsync(deg_r, 0, (size_t)NREP * Npad * sizeof(int), stream);

    const int NB = (N + 255) / 256;
    const int GB = (N + 63) / 64;
    dim3 b256(256);

    // fused node transform + replicated degree histogram (independent work)
    k_gemm1h<<<dim3(3 * GB), b256, 0, stream>>>(
        x, W1, att_s1, att_d1, h1b, a_src1, a_dst1, N, Npad, GB,
        dst, deg_r, rank, E);
    // CSR build: replica prefix + totals, block sums, scan, rowptr, fill
    k_bsum<<<dim3(NB), b256, 0, stream>>>(deg_r, pre, deg_total, bsum, N, Npad);
    k_scan_bsum<<<dim3(1), dim3(512), 0, stream>>>(bsum, bexc, NB);
    k_rowptr<<<dim3(NB), b256, 0, stream>>>(deg_total, bexc, rowptr, N, (int)E);
    k_fill<<<dim3((unsigned)((E + 1023) / 1024)), b256, 0, stream>>>(
        src, dst, rank, rowptr, pre, csr, Npad, E);

    // Layer 1 aggregate
    k_gather1<<<dim3((N + 3) / 4), b256, 0, stream>>>(
        rowptr, csr, h1b, a_src1, a_dst1, agg1, N);

    // emb output + layer-2 prologue
    float* emb = (float*)d_out;               // N*64
    float* lsm = emb + (size_t)N * HD;        // N*7
    k_node2<<<dim3(NB), b256, 0, stream>>>(
        agg1, b1, W2, att_s2, att_d2, emb, h2p, a_src2, a_dst2, N);

    // Layer 2 aggregate + fused log_softmax
    k_gather2<<<dim3((N + 3) / 4), b256, 0, stream>>>(
        rowptr, csr, h2p, a_src2, a_dst2, b2, lsm, N);
}

// Round 10
// 626.226 us; speedup vs baseline: 1.0334x; 1.0334x over previous
//
#include <hip/hip_runtime.h>
#include <hip/hip_bf16.h>
#include <math.h>

#define F_IN 128
#define HD   64    // H*D layer1
#define NH   8
#define DH   8
#define NC   7     // classes

typedef __attribute__((ext_vector_type(8))) short short8v;  // 8 bf16 (4 VGPR)
typedef __attribute__((ext_vector_type(4))) float f32x4;

__device__ __forceinline__ float lrelu(float e) { return fmaxf(e, 0.2f * e); }
__device__ __forceinline__ ushort f2bf(float f) {
    unsigned u = __float_as_uint(f);
    unsigned rounded = u + 0x7FFF + ((u >> 16) & 1);
    return (ushort)(rounded >> 16);
}

// ---- K0: W1 -> bf16 hi/lo, laid out in MFMA B-fragment order ----------------
// B-frag (16x16x32): lane l holds B[k=8*(l>>4)+i][col=l&15], i=0..7.
// Frag buffer index: ((ct*4+ks)*64 + lane)*8 + i  (ct=coltile, ks=kstep).
__global__ __launch_bounds__(256) void k_wcvt(
    const float* __restrict__ W1, ushort* __restrict__ Wh, ushort* __restrict__ Wl)
{
    int t = threadIdx.x;
    for (int g = t; g < 8192; g += 256) {
        int i = g & 7, lane = (g >> 3) & 63, fs = g >> 9;
        int ct = fs >> 2, ks = fs & 3;
        int k = (ks << 5) + ((lane >> 4) << 3) + i;
        int c = (ct << 4) + (lane & 15);
        float w = W1[k * HD + c];
        ushort wh = f2bf(w);
        float whf = __uint_as_float((uint)wh << 16);
        Wh[g] = wh;
        Wl[g] = f2bf(w - whf);
    }
}

// ---------- K1 fused: gemm1 (bid%3==0) + hist (else) -------------------------
// v7: MFMA gemm.  Old v2/v3/v5 all pinned at ~150us because the broadcast-LDS
// structure issues 4096 b128 LDS ops/block = ~125us of LDS-pipe occupancy/CU
// (per-instruction cost; 64-lane broadcast wastes 63/64 of the port).
// Now: h = xh@Wh + xl@Wh + xh@Wl via mfma_f32_16x16x32_bf16 (hi/lo split,
// dropped xl@Wl ~4e-5 << bf16-storage absmax).  A-frags converted inline from
// x (fp32); B-frags preconverted by k_wcvt.  ZERO LDS, MFMA pipe was idle.
// Layouts (m89-verified family): A: row=l&15, k=8*(l>>4)+i; B: col=l&15,
// k=8*(l>>4)+i; D: col=l&15, row=4*(l>>4)+reg.
// hist branch: R8's proven grid-stride form (replication reverted: R9 showed
// same-address atomic serialization is NOT the bottleneck).
__global__ __launch_bounds__(256) void k_gemm1h(
    const float* __restrict__ x,
    const ushort* __restrict__ Wh, const ushort* __restrict__ Wl,
    const float* __restrict__ att_src, const float* __restrict__ att_dst,
    ushort* __restrict__ h1b, float* __restrict__ a_src, float* __restrict__ a_dst,
    int N, int GB,
    const int* __restrict__ dstArr, int* __restrict__ deg, int* __restrict__ rank,
    long E)
{
    int t = threadIdx.x;
    int bid = blockIdx.x;

    if (bid % 3 != 0) {
        // ---- hist branch: grid-stride over edges ----
        long hb = (long)(bid / 3) * 2 + (bid % 3) - 1;    // [0, 2*GB)
        long stride = (long)(2 * GB) * 256;
        for (long i = hb * 256 + t; i < E; i += stride)
            rank[i] = atomicAdd(&deg[dstArr[i]], 1);
        return;
    }

    int gb = bid / 3;                                     // [0, GB)
    int lane = t & 63;
    int wave = t >> 6;
    int base = gb * 64 + wave * 16;                       // this wave: 16 rows
    if (base >= N) return;                                // wave-uniform exit

    int arow = base + (lane & 15);                        // A-frag row
    if (arow >= N) arow = N - 1;                          // clamp (stores guarded)
    int kg = lane >> 4;                                   // k-group

    f32x4 acc[4];
    #pragma unroll
    for (int ct = 0; ct < 4; ++ct) acc[ct] = (f32x4){0.f, 0.f, 0.f, 0.f};

    #pragma unroll
    for (int ks = 0; ks < 4; ++ks) {
        const float* xp = x + (size_t)arow * F_IN + ks * 32 + kg * 8;
        float4 xa = *(const float4*)xp;
        float4 xb = *(const float4*)(xp + 4);
        float xs[8] = {xa.x, xa.y, xa.z, xa.w, xb.x, xb.y, xb.z, xb.w};
        short8v ah, al;
        #pragma unroll
        for (int i = 0; i < 8; ++i) {
            ushort hh = f2bf(xs[i]);
            ah[i] = (short)hh;
            float hf = __uint_as_float((uint)hh << 16);
            al[i] = (short)f2bf(xs[i] - hf);
        }
        #pragma unroll
        for (int ct = 0; ct < 4; ++ct) {
            size_t fo = (size_t)((ct * 4 + ks) * 64 + lane) * 8;
            short8v bh = *(const short8v*)(Wh + fo);
            short8v bl = *(const short8v*)(Wl + fo);
            acc[ct] = __builtin_amdgcn_mfma_f32_16x16x32_bf16(ah, bh, acc[ct], 0, 0, 0);
            acc[ct] = __builtin_amdgcn_mfma_f32_16x16x32_bf16(al, bh, acc[ct], 0, 0, 0);
            acc[ct] = __builtin_amdgcn_mfma_f32_16x16x32_bf16(ah, bl, acc[ct], 0, 0, 0);
        }
    }

    // epilogue: D lane mapping col = ct*16 + (lane&15), row = base + 4*(lane>>4)+r
    int rg = lane >> 4;
    int cl = lane & 15;
    #pragma unroll
    for (int ct = 0; ct < 4; ++ct) {
        int c = ct * 16 + cl;
        float asv = att_src[c];
        float adv = att_dst[c];
        #pragma unroll
        for (int r = 0; r < 4; ++r) {
            int row = base + rg * 4 + r;
            float v = acc[ct][r];
            if (row < N) h1b[(size_t)row * HD + c] = f2bf(v);
            float vs = v * asv;
            float vd = v * adv;
            vs += __shfl_xor(vs, 1, 64); vd += __shfl_xor(vd, 1, 64);
            vs += __shfl_xor(vs, 2, 64); vd += __shfl_xor(vd, 2, 64);
            vs += __shfl_xor(vs, 4, 64); vd += __shfl_xor(vd, 4, 64);
            if ((lane & 7) == 0 && row < N) {
                int head = 2 * ct + ((lane >> 3) & 1);
                a_src[row * NH + head] = vs;
                a_dst[row * NH + head] = vd;
            }
        }
    }
}

// ---------------- CSR build (R8 form) ----------------------------------------
__global__ __launch_bounds__(256) void k_bsum(
    const int* __restrict__ deg, int* __restrict__ bsum, int N)
{
    __shared__ int s[256];
    int t = threadIdx.x;
    int i = blockIdx.x * 256 + t;
    s[t] = (i < N) ? deg[i] : 0;
    __syncthreads();
    #pragma unroll
    for (int o = 128; o > 0; o >>= 1) {
        if (t < o) s[t] += s[t + o];
        __syncthreads();
    }
    if (t == 0) bsum[blockIdx.x] = s[0];
}

__global__ __launch_bounds__(512) void k_scan_bsum(
    const int* __restrict__ bsum, int* __restrict__ bexc, int NB)
{
    __shared__ int s[512];
    int t = threadIdx.x;
    s[t] = (t < NB) ? bsum[t] : 0;
    __syncthreads();
    for (int o = 1; o < 512; o <<= 1) {
        int v = (t >= o) ? s[t - o] : 0;
        __syncthreads();
        s[t] += v;
        __syncthreads();
    }
    if (t < NB) bexc[t] = (t == 0) ? 0 : s[t - 1];
}

__global__ __launch_bounds__(256) void k_rowptr(
    const int* __restrict__ deg, const int* __restrict__ bexc,
    int* __restrict__ rowptr, int N, int Etot)
{
    __shared__ int s[256];
    int t = threadIdx.x;
    int i = blockIdx.x * 256 + t;
    int v = (i < N) ? deg[i] : 0;
    s[t] = v;
    __syncthreads();
    for (int o = 1; o < 256; o <<= 1) {
        int u = (t >= o) ? s[t - o] : 0;
        __syncthreads();
        s[t] += u;
        __syncthreads();
    }
    if (i < N) rowptr[i] = bexc[blockIdx.x] + s[t] - v;  // exclusive
    if (i == 0) rowptr[N] = Etot;
}

// v2: 4 edges/thread, int4 loads, 4 scattered stores in flight
__global__ __launch_bounds__(256) void k_fill(
    const int* __restrict__ src, const int* __restrict__ dst,
    const int* __restrict__ rank, const int* __restrict__ rowptr,
    int* __restrict__ csr, long E)
{
    long i4 = ((long)blockIdx.x * 256 + threadIdx.x) * 4;
    if (i4 >= E) return;
    if (i4 + 3 < E) {
        int4 d4 = *(const int4*)(dst + i4);
        int4 r4 = *(const int4*)(rank + i4);
        int4 s4 = *(const int4*)(src + i4);
        int p0 = rowptr[d4.x], p1 = rowptr[d4.y];
        int p2 = rowptr[d4.z], p3 = rowptr[d4.w];
        csr[p0 + r4.x] = s4.x;
        csr[p1 + r4.y] = s4.y;
        csr[p2 + r4.z] = s4.z;
        csr[p3 + r4.w] = s4.w;
    } else {
        for (long i = i4; i < E; ++i)
            csr[rowptr[dst[i]] + rank[i]] = src[i];
    }
}

// ---------------- K-gather1 v6: wave per dst, lane=(e,h), 3-stage pipeline ---
__global__ __launch_bounds__(256) void k_gather1(
    const int* __restrict__ rowptr, const int* __restrict__ csr,
    const ushort* __restrict__ h1b, const float* __restrict__ a_src,
    const float* __restrict__ a_dst, float* __restrict__ agg, int N)
{
    const uint* __restrict__ h1u = (const uint*)h1b;
    int wave = threadIdx.x >> 6, lane = threadIdx.x & 63;
    int d = blockIdx.x * 4 + wave;
    if (d >= N) return;
    int e = lane >> 3;           // edge slot
    int h = lane & 7;            // head; channels 8h..8h+7 = dwords 4h..4h+3

    float adst = a_dst[d * NH + h];
    float ws = __expf(lrelu(a_src[d * NH + h] + adst));   // self-loop weight
    float wsum = (e == 0) ? ws : 0.f;

    float ax0 = 0.f, ay0 = 0.f, ax1 = 0.f, ay1 = 0.f;
    float ax2 = 0.f, ay2 = 0.f, ax3 = 0.f, ay3 = 0.f;
    if (e == 0) {
        size_t b = (size_t)d * 32 + h * 4;
        uint u0 = h1u[b], u1 = h1u[b + 1], u2 = h1u[b + 2], u3 = h1u[b + 3];
        ax0 = ws * __uint_as_float(u0 << 16); ay0 = ws * __uint_as_float(u0 & 0xFFFF0000u);
        ax1 = ws * __uint_as_float(u1 << 16); ay1 = ws * __uint_as_float(u1 & 0xFFFF0000u);
        ax2 = ws * __uint_as_float(u2 << 16); ay2 = ws * __uint_as_float(u2 & 0xFFFF0000u);
        ax3 = ws * __uint_as_float(u3 << 16); ay3 = ws * __uint_as_float(u3 & 0xFFFF0000u);
    }

    int jb = rowptr[d], je = rowptr[d + 1];

    // ---- pipeline prologue ----
    int  idx0 = jb + e;
    bool v0   = idx0 < je;
    int  sl0  = v0 ? csr[idx0] : d;
    float as0 = a_src[sl0 * NH + h];
    size_t b0 = (size_t)sl0 * 32 + h * 4;
    uint u0 = h1u[b0], u1 = h1u[b0 + 1], u2 = h1u[b0 + 2], u3 = h1u[b0 + 3];

    int  idx1 = jb + 8 + e;
    bool v1   = idx1 < je;
    int  sl1  = v1 ? csr[idx1] : d;
    float as1 = a_src[sl1 * NH + h];

    int  idx2 = jb + 16 + e;
    bool v2   = idx2 < je;
    int  sl2  = v2 ? csr[idx2] : d;

    for (int j0 = jb; j0 < je; j0 += 8) {
        int  idx3 = j0 + 24 + e;
        bool v3   = idx3 < je;
        int  sl3  = v3 ? csr[idx3] : d;
        float as2 = a_src[sl2 * NH + h];
        size_t b1 = (size_t)sl1 * 32 + h * 4;
        uint n0 = h1u[b1], n1 = h1u[b1 + 1], n2 = h1u[b1 + 2], n3 = h1u[b1 + 3];

        float w = v0 ? __expf(lrelu(as0 + adst)) : 0.f;
        wsum += w;
        ax0 += w * __uint_as_float(u0 << 16); ay0 += w * __uint_as_float(u0 & 0xFFFF0000u);
        ax1 += w * __uint_as_float(u1 << 16); ay1 += w * __uint_as_float(u1 & 0xFFFF0000u);
        ax2 += w * __uint_as_float(u2 << 16); ay2 += w * __uint_as_float(u2 & 0xFFFF0000u);
        ax3 += w * __uint_as_float(u3 << 16); ay3 += w * __uint_as_float(u3 & 0xFFFF0000u);

        v0 = v1; as0 = as1; u0 = n0; u1 = n1; u2 = n2; u3 = n3;
        v1 = v2; sl1 = sl2; as1 = as2;
        v2 = v3; sl2 = sl3;
    }

    #pragma unroll
    for (int o = 8; o <= 32; o <<= 1) {
        wsum += __shfl_xor(wsum, o, 64);
        ax0 += __shfl_xor(ax0, o, 64); ay0 += __shfl_xor(ay0, o, 64);
        ax1 += __shfl_xor(ax1, o, 64); ay1 += __shfl_xor(ay1, o, 64);
        ax2 += __shfl_xor(ax2, o, 64); ay2 += __shfl_xor(ay2, o, 64);
        ax3 += __shfl_xor(ax3, o, 64); ay3 += __shfl_xor(ay3, o, 64);
    }
    if (e == 0) {
        float winv = 1.f / (wsum + 1e-16f);
        float* op = agg + (size_t)d * HD + h * 8;
        *(float4*)(op)     = make_float4(ax0 * winv, ay0 * winv, ax1 * winv, ay1 * winv);
        *(float4*)(op + 4) = make_float4(ax2 * winv, ay2 * winv, ax3 * winv, ay3 * winv);
    }
}

// ------- K4: emb = agg1+b1 (OUT0); x2 = elu(emb); h2p = x2@W2; a_*2 ----------
__global__ __launch_bounds__(256) void k_node2(
    const float* __restrict__ agg1, const float* __restrict__ b1,
    const float* __restrict__ W2, const float* __restrict__ att_s2,
    const float* __restrict__ att_d2, float* __restrict__ emb_out,
    float* __restrict__ h2p, float* __restrict__ a_src2, float* __restrict__ a_dst2,
    int N)
{
    __shared__ float sW[HD * NC];
    __shared__ float sb[HD];
    __shared__ float sas[NC], sad[NC];
    int t = threadIdx.x;
    for (int i = t; i < HD * NC; i += 256) sW[i] = W2[i];
    if (t < HD) sb[t] = b1[t];
    if (t < NC) { sas[t] = att_s2[t]; sad[t] = att_d2[t]; }
    __syncthreads();
    int n = blockIdx.x * 256 + t;
    if (n >= N) return;
    const float* ag = agg1 + (size_t)n * HD;
    float* eo = emb_out + (size_t)n * HD;
    float acc[NC];
    #pragma unroll
    for (int c = 0; c < NC; ++c) acc[c] = 0.f;
    #pragma unroll 8
    for (int k = 0; k < HD; ++k) {
        float v = ag[k] + sb[k];
        eo[k] = v;
        float xv = v > 0.f ? v : expm1f(v);   // jax.nn.elu
        #pragma unroll
        for (int c = 0; c < NC; ++c) acc[c] += xv * sW[k * NC + c];
    }
    float as = 0.f, ad = 0.f;
    float* hp = h2p + (size_t)n * 8;
    #pragma unroll
    for (int c = 0; c < NC; ++c) {
        hp[c] = acc[c];
        as += acc[c] * sas[c];
        ad += acc[c] * sad[c];
    }
    hp[7] = 0.f;
    a_src2[n] = as;
    a_dst2[n] = ad;
}

// ------- K-gather2 v2: WAVE per dst; depth-2 pipeline (as/hv one ahead) ------
__global__ __launch_bounds__(256) void k_gather2(
    const int* __restrict__ rowptr, const int* __restrict__ csr,
    const float* __restrict__ h2p, const float* __restrict__ a_src2,
    const float* __restrict__ a_dst2, const float* __restrict__ b2,
    float* __restrict__ out, int N)
{
    int t = threadIdx.x;
    int wave = t >> 6, lane = t & 63;
    int g = lane >> 3;           // edge slot 0..7
    int c = lane & 7;            // channel (7 = pad)
    int n = blockIdx.x * 4 + wave;
    if (n >= N) return;
    float ad = a_dst2[n];
    float w = __expf(lrelu(a_src2[n] + ad));   // self-loop
    float acc  = (g == 0) ? w * h2p[(size_t)n * 8 + c] : 0.f;
    float wsum = (g == 0) ? w : 0.f;
    int jb = rowptr[n], je = rowptr[n + 1];

    int  idx0 = jb + g;
    bool v0   = idx0 < je;
    int  s0   = v0 ? csr[idx0] : n;
    float as0 = a_src2[s0];
    float hv0 = h2p[(size_t)s0 * 8 + c];

    int  idx1 = jb + 8 + g;
    bool v1   = idx1 < je;
    int  s1   = v1 ? csr[idx1] : n;

    for (int j = jb; j < je; j += 8) {
        int  idx2 = j + 16 + g;
        bool v2   = idx2 < je;
        int  s2   = v2 ? csr[idx2] : n;
        float as1 = a_src2[s1];
        float hv1 = h2p[(size_t)s1 * 8 + c];
        float ww = v0 ? __expf(lrelu(as0 + ad)) : 0.f;
        acc += ww * hv0;
        wsum += ww;
        v0 = v1; as0 = as1; hv0 = hv1;
        v1 = v2; s1 = s2;
    }
    #pragma unroll
    for (int o = 32; o >= 8; o >>= 1) {
        acc  += __shfl_xor(acc, o, 64);
        wsum += __shfl_xor(wsum, o, 64);
    }
    float l = (c < NC) ? (acc / (wsum + 1e-16f) + b2[c]) : -1e30f;
    float m = l;
    #pragma unroll
    for (int o = 4; o > 0; o >>= 1) m = fmaxf(m, __shfl_xor(m, o, 8));
    float ex = (c < NC) ? __expf(l - m) : 0.f;
    float s8 = ex;
    #pragma unroll
    for (int o = 4; o > 0; o >>= 1) s8 += __shfl_xor(s8, o, 8);
    if (g == 0 && c < NC) out[(size_t)n * NC + c] = l - m - logf(s8);
}

extern "C" void kernel_launch(void* const* d_in, const int* in_sizes, int n_in,
                              void* d_out, int out_size, void* d_ws, size_t ws_size,
                              hipStream_t stream)
{
    const float* x       = (const float*)d_in[0];
    const int*   ei      = (const int*)d_in[1];
    const float* W1      = (const float*)d_in[2];
    const float* att_s1  = (const float*)d_in[3];
    const float* att_d1  = (const float*)d_in[4];
    const float* b1      = (const float*)d_in[5];
    const float* W2      = (const float*)d_in[6];
    const float* att_s2  = (const float*)d_in[7];
    const float* att_d2  = (const float*)d_in[8];
    const float* b2      = (const float*)d_in[9];

    const int  N = in_sizes[0] / F_IN;
    const long E = (long)in_sizes[1] / 2;
    const int* src = ei;
    const int* dst = ei + E;

    const int Npad  = (N + 3) & ~3;
    const int Np1p  = (N + 4) & ~3;
    const long Epad = (E + 3) & ~3;

    // ---- workspace layout (R8) ----
    int* deg    = (int*)d_ws;                 // Npad   (zeroed)
    int* rowptr = deg + Npad;                 // N+1
    int* bexc   = rowptr + Np1p;              // 512
    int* bsum   = bexc + 512;                 // 512
    int* csr    = bsum + 512;                 // E
    ushort* h1b   = (ushort*)(csr + Epad);    // Npad*64 bf16
    float* a_src1 = (float*)(h1b + (size_t)Npad * HD); // N*8
    float* a_dst1 = a_src1 + (size_t)N * NH;  // N*8
    float* agg1   = a_dst1 + (size_t)N * NH;  // N*64
    float* h2p    = agg1 + (size_t)N * HD;    // N*8 (padded NC->8)
    float* a_src2 = h2p + (size_t)N * 8;      // Npad
    float* a_dst2 = a_src2 + Npad;            // Npad
    float* wsend  = a_dst2 + Npad;
    // rank[E] aliases agg1 (dead before k_gather1 writes agg1; E <= N*HD)
    int* rank = (E <= (long)N * HD) ? (int*)agg1 : (int*)wsend;
    // W1 hi/lo frag buffers alias a_src2 block (written by k_wcvt before gemm,
    // dead before k_node2 writes a_src2; 32KB << Npad*4B)
    ushort* Wh = (ushort*)a_src2;             // 8192 ushort
    ushort* Wl = Wh + 8192;                   // 8192 ushort

    hipMemsetAsync(deg, 0, (size_t)Npad * sizeof(int), stream);

    const int NB = (N + 255) / 256;
    const int GB = (N + 63) / 64;
    dim3 b256(256);

    // W1 -> bf16 hi/lo fragments
    k_wcvt<<<dim3(1), b256, 0, stream>>>(W1, Wh, Wl);

    // fused MFMA node transform + degree histogram (independent work)
    k_gemm1h<<<dim3(3 * GB), b256, 0, stream>>>(
        x, Wh, Wl, att_s1, att_d1, h1b, a_src1, a_dst1, N, GB,
        dst, deg, rank, E);
    // CSR build
    k_bsum<<<dim3(NB), b256, 0, stream>>>(deg, bsum, N);
    k_scan_bsum<<<dim3(1), dim3(512), 0, stream>>>(bsum, bexc, NB);
    k_rowptr<<<dim3(NB), b256, 0, stream>>>(deg, bexc, rowptr, N, (int)E);
    k_fill<<<dim3((unsigned)((E + 1023) / 1024)), b256, 0, stream>>>(
        src, dst, rank, rowptr, csr, E);

    // Layer 1 aggregate
    k_gather1<<<dim3((N + 3) / 4), b256, 0, stream>>>(
        rowptr, csr, h1b, a_src1, a_dst1, agg1, N);

    // emb output + layer-2 prologue
    float* emb = (float*)d_out;               // N*64
    float* lsm = emb + (size_t)N * HD;        // N*7
    k_node2<<<dim3(NB), b256, 0, stream>>>(
        agg1, b1, W2, att_s2, att_d2, emb, h2p, a_src2, a_dst2, N);

    // Layer 2 aggregate + fused log_softmax
    k_gather2<<<dim3((N + 3) / 4), b256, 0, stream>>>(
        rowptr, csr, h2p, a_src2, a_dst2, b2, lsm, N);
}

// Round 11
// 575.345 us; speedup vs baseline: 1.1247x; 1.0884x over previous
//
#include <hip/hip_runtime.h>
#include <hip/hip_bf16.h>
#include <math.h>

#define F_IN 128
#define HD   64    // H*D layer1
#define NH   8
#define DH   8
#define NC   7     // classes
#define CAP  64    // fixed CSR row capacity (deg ~ Poisson(32); P(>64)~1.4e-7)
#define OVF_CAP 8192

typedef __attribute__((ext_vector_type(8))) short short8v;  // 8 bf16 (4 VGPR)
typedef __attribute__((ext_vector_type(4))) float f32x4;

__device__ __forceinline__ float lrelu(float e) { return fmaxf(e, 0.2f * e); }
__device__ __forceinline__ ushort f2bf(float f) {
    unsigned u = __float_as_uint(f);
    unsigned rounded = u + 0x7FFF + ((u >> 16) & 1);
    return (ushort)(rounded >> 16);
}

// ---- K0: W1 -> bf16 hi/lo, laid out in MFMA B-fragment order ----------------
__global__ __launch_bounds__(256) void k_wcvt(
    const float* __restrict__ W1, ushort* __restrict__ Wh, ushort* __restrict__ Wl)
{
    int t = threadIdx.x;
    for (int g = t; g < 8192; g += 256) {
        int i = g & 7, lane = (g >> 3) & 63, fs = g >> 9;
        int ct = fs >> 2, ks = fs & 3;
        int k = (ks << 5) + ((lane >> 4) << 3) + i;
        int c = (ct << 4) + (lane & 15);
        float w = W1[k * HD + c];
        ushort wh = f2bf(w);
        float whf = __uint_as_float((uint)wh << 16);
        Wh[g] = wh;
        Wl[g] = f2bf(w - whf);
    }
}

// ---------- K1 fused: MFMA gemm1 (bid%3==0) + CSR scatter (else) -------------
// R10 evidence: with gemm at VALU 5%/MFMA 1.3%/LDS 0, the kernel still takes
// 141us and WRITE_SIZE=133MB (~100MB = 3.2M x 32B atomic write-through).  The
// returning-atomic pass has a hard write-traffic floor -- so spend it ONCE:
// one-pass fixed-capacity CSR.  csrF[dst*CAP + atomicAdd(&cnt[dst],1)] = src.
// Return value = rank, final cnt = degree, row base = dst*CAP -> k_bsum,
// k_scan, k_rowptr, k_fill and rank[] are all DELETED.  Overflow (>CAP per
// row, expected ~0.01 nodes) goes to a tiny exact side list.
__global__ __launch_bounds__(256) void k_gemm1h(
    const float* __restrict__ x,
    const ushort* __restrict__ Wh, const ushort* __restrict__ Wl,
    const float* __restrict__ att_src, const float* __restrict__ att_dst,
    ushort* __restrict__ h1b, float* __restrict__ a_src, float* __restrict__ a_dst,
    int N, int GB,
    const int* __restrict__ srcArr, const int* __restrict__ dstArr,
    int* __restrict__ cnt, int* __restrict__ csrF,
    int* __restrict__ ovfn, int* __restrict__ ovf,
    long E)
{
    int t = threadIdx.x;
    int bid = blockIdx.x;

    if (bid % 3 != 0) {
        // ---- scatter branch: grid-stride over edges ----
        long hb = (long)(bid / 3) * 2 + (bid % 3) - 1;    // [0, 2*GB)
        long stride = (long)(2 * GB) * 256;
        for (long i = hb * 256 + t; i < E; i += stride) {
            int d = dstArr[i];
            int s = srcArr[i];
            int idx = atomicAdd(&cnt[d], 1);
            if (idx < CAP) {
                csrF[(size_t)d * CAP + idx] = s;
            } else {
                int o = atomicAdd(ovfn, 1);
                if (o < OVF_CAP) { ovf[2 * o] = d; ovf[2 * o + 1] = s; }
            }
        }
        return;
    }

    int gb = bid / 3;                                     // [0, GB)
    int lane = t & 63;
    int wave = t >> 6;
    int base = gb * 64 + wave * 16;                       // this wave: 16 rows
    if (base >= N) return;                                // wave-uniform exit

    int arow = base + (lane & 15);                        // A-frag row
    if (arow >= N) arow = N - 1;                          // clamp (stores guarded)
    int kg = lane >> 4;                                   // k-group

    f32x4 acc[4];
    #pragma unroll
    for (int ct = 0; ct < 4; ++ct) acc[ct] = (f32x4){0.f, 0.f, 0.f, 0.f};

    #pragma unroll
    for (int ks = 0; ks < 4; ++ks) {
        const float* xp = x + (size_t)arow * F_IN + ks * 32 + kg * 8;
        float4 xa = *(const float4*)xp;
        float4 xb = *(const float4*)(xp + 4);
        float xs[8] = {xa.x, xa.y, xa.z, xa.w, xb.x, xb.y, xb.z, xb.w};
        short8v ah, al;
        #pragma unroll
        for (int i = 0; i < 8; ++i) {
            ushort hh = f2bf(xs[i]);
            ah[i] = (short)hh;
            float hf = __uint_as_float((uint)hh << 16);
            al[i] = (short)f2bf(xs[i] - hf);
        }
        #pragma unroll
        for (int ct = 0; ct < 4; ++ct) {
            size_t fo = (size_t)((ct * 4 + ks) * 64 + lane) * 8;
            short8v bh = *(const short8v*)(Wh + fo);
            short8v bl = *(const short8v*)(Wl + fo);
            acc[ct] = __builtin_amdgcn_mfma_f32_16x16x32_bf16(ah, bh, acc[ct], 0, 0, 0);
            acc[ct] = __builtin_amdgcn_mfma_f32_16x16x32_bf16(al, bh, acc[ct], 0, 0, 0);
            acc[ct] = __builtin_amdgcn_mfma_f32_16x16x32_bf16(ah, bl, acc[ct], 0, 0, 0);
        }
    }

    // epilogue: D lane mapping col = ct*16 + (lane&15), row = base + 4*(lane>>4)+r
    int rg = lane >> 4;
    int cl = lane & 15;
    #pragma unroll
    for (int ct = 0; ct < 4; ++ct) {
        int c = ct * 16 + cl;
        float asv = att_src[c];
        float adv = att_dst[c];
        #pragma unroll
        for (int r = 0; r < 4; ++r) {
            int row = base + rg * 4 + r;
            float v = acc[ct][r];
            if (row < N) h1b[(size_t)row * HD + c] = f2bf(v);
            float vs = v * asv;
            float vd = v * adv;
            vs += __shfl_xor(vs, 1, 64); vd += __shfl_xor(vd, 1, 64);
            vs += __shfl_xor(vs, 2, 64); vd += __shfl_xor(vd, 2, 64);
            vs += __shfl_xor(vs, 4, 64); vd += __shfl_xor(vd, 4, 64);
            if ((lane & 7) == 0 && row < N) {
                int head = 2 * ct + ((lane >> 3) & 1);
                a_src[row * NH + head] = vs;
                a_dst[row * NH + head] = vd;
            }
        }
    }
}

// ---------------- K-gather1: wave per dst, lane=(e,h), 3-stage pipeline ------
// Row d = csrF[d*CAP .. d*CAP+min(cnt[d],CAP));  overflow entries (rare:
// expected ~0) appended from the exact side list.
__global__ __launch_bounds__(256) void k_gather1(
    const int* __restrict__ cnt, const int* __restrict__ csrF,
    const int* __restrict__ ovfn, const int* __restrict__ ovf,
    const ushort* __restrict__ h1b, const float* __restrict__ a_src,
    const float* __restrict__ a_dst, float* __restrict__ agg, int N)
{
    const uint* __restrict__ h1u = (const uint*)h1b;
    int wave = threadIdx.x >> 6, lane = threadIdx.x & 63;
    int d = blockIdx.x * 4 + wave;
    if (d >= N) return;
    int e = lane >> 3;           // edge slot
    int h = lane & 7;            // head; channels 8h..8h+7 = dwords 4h..4h+3

    float adst = a_dst[d * NH + h];
    float ws = __expf(lrelu(a_src[d * NH + h] + adst));   // self-loop weight
    float wsum = (e == 0) ? ws : 0.f;

    float ax0 = 0.f, ay0 = 0.f, ax1 = 0.f, ay1 = 0.f;
    float ax2 = 0.f, ay2 = 0.f, ax3 = 0.f, ay3 = 0.f;
    if (e == 0) {
        size_t b = (size_t)d * 32 + h * 4;
        uint u0 = h1u[b], u1 = h1u[b + 1], u2 = h1u[b + 2], u3 = h1u[b + 3];
        ax0 = ws * __uint_as_float(u0 << 16); ay0 = ws * __uint_as_float(u0 & 0xFFFF0000u);
        ax1 = ws * __uint_as_float(u1 << 16); ay1 = ws * __uint_as_float(u1 & 0xFFFF0000u);
        ax2 = ws * __uint_as_float(u2 << 16); ay2 = ws * __uint_as_float(u2 & 0xFFFF0000u);
        ax3 = ws * __uint_as_float(u3 << 16); ay3 = ws * __uint_as_float(u3 & 0xFFFF0000u);
    }

    int m = cnt[d]; if (m > CAP) m = CAP;
    int jb = d * CAP, je = jb + m;

    // ---- pipeline prologue ----
    int  idx0 = jb + e;
    bool v0   = idx0 < je;
    int  sl0  = v0 ? csrF[idx0] : d;
    float as0 = a_src[sl0 * NH + h];
    size_t b0 = (size_t)sl0 * 32 + h * 4;
    uint u0 = h1u[b0], u1 = h1u[b0 + 1], u2 = h1u[b0 + 2], u3 = h1u[b0 + 3];

    int  idx1 = jb + 8 + e;
    bool v1   = idx1 < je;
    int  sl1  = v1 ? csrF[idx1] : d;
    float as1 = a_src[sl1 * NH + h];

    int  idx2 = jb + 16 + e;
    bool v2   = idx2 < je;
    int  sl2  = v2 ? csrF[idx2] : d;

    for (int j0 = jb; j0 < je; j0 += 8) {
        int  idx3 = j0 + 24 + e;
        bool v3   = idx3 < je;
        int  sl3  = v3 ? csrF[idx3] : d;
        float as2 = a_src[sl2 * NH + h];
        size_t b1 = (size_t)sl1 * 32 + h * 4;
        uint n0 = h1u[b1], n1 = h1u[b1 + 1], n2 = h1u[b1 + 2], n3 = h1u[b1 + 3];

        float w = v0 ? __expf(lrelu(as0 + adst)) : 0.f;
        wsum += w;
        ax0 += w * __uint_as_float(u0 << 16); ay0 += w * __uint_as_float(u0 & 0xFFFF0000u);
        ax1 += w * __uint_as_float(u1 << 16); ay1 += w * __uint_as_float(u1 & 0xFFFF0000u);
        ax2 += w * __uint_as_float(u2 << 16); ay2 += w * __uint_as_float(u2 & 0xFFFF0000u);
        ax3 += w * __uint_as_float(u3 << 16); ay3 += w * __uint_as_float(u3 & 0xFFFF0000u);

        v0 = v1; as0 = as1; u0 = n0; u1 = n1; u2 = n2; u3 = n3;
        v1 = v2; sl1 = sl2; as1 = as2;
        v2 = v3; sl2 = sl3;
    }

    // ---- overflow entries (expected none; exactness guard) ----
    int no = *ovfn;
    if (no > 0) {
        if (no > OVF_CAP) no = OVF_CAP;
        for (int k2 = 0; k2 < no; ++k2) {
            int od = ovf[2 * k2], os = ovf[2 * k2 + 1];
            if (od == d && e == 0) {
                float w = __expf(lrelu(a_src[os * NH + h] + adst));
                wsum += w;
                size_t bb = (size_t)os * 32 + h * 4;
                uint o0 = h1u[bb], o1 = h1u[bb + 1], o2 = h1u[bb + 2], o3 = h1u[bb + 3];
                ax0 += w * __uint_as_float(o0 << 16); ay0 += w * __uint_as_float(o0 & 0xFFFF0000u);
                ax1 += w * __uint_as_float(o1 << 16); ay1 += w * __uint_as_float(o1 & 0xFFFF0000u);
                ax2 += w * __uint_as_float(o2 << 16); ay2 += w * __uint_as_float(o2 & 0xFFFF0000u);
                ax3 += w * __uint_as_float(o3 << 16); ay3 += w * __uint_as_float(o3 & 0xFFFF0000u);
            }
        }
    }

    // epilogue: reduce over edge slots (xor bits 3..5 keeps h fixed)
    #pragma unroll
    for (int o = 8; o <= 32; o <<= 1) {
        wsum += __shfl_xor(wsum, o, 64);
        ax0 += __shfl_xor(ax0, o, 64); ay0 += __shfl_xor(ay0, o, 64);
        ax1 += __shfl_xor(ax1, o, 64); ay1 += __shfl_xor(ay1, o, 64);
        ax2 += __shfl_xor(ax2, o, 64); ay2 += __shfl_xor(ay2, o, 64);
        ax3 += __shfl_xor(ax3, o, 64); ay3 += __shfl_xor(ay3, o, 64);
    }
    if (e == 0) {
        float winv = 1.f / (wsum + 1e-16f);
        float* op = agg + (size_t)d * HD + h * 8;
        *(float4*)(op)     = make_float4(ax0 * winv, ay0 * winv, ax1 * winv, ay1 * winv);
        *(float4*)(op + 4) = make_float4(ax2 * winv, ay2 * winv, ax3 * winv, ay3 * winv);
    }
}

// ------- K4: emb = agg1+b1 (OUT0); x2 = elu(emb); h2p = x2@W2; a_*2 ----------
__global__ __launch_bounds__(256) void k_node2(
    const float* __restrict__ agg1, const float* __restrict__ b1,
    const float* __restrict__ W2, const float* __restrict__ att_s2,
    const float* __restrict__ att_d2, float* __restrict__ emb_out,
    float* __restrict__ h2p, float* __restrict__ a_src2, float* __restrict__ a_dst2,
    int N)
{
    __shared__ float sW[HD * NC];
    __shared__ float sb[HD];
    __shared__ float sas[NC], sad[NC];
    int t = threadIdx.x;
    for (int i = t; i < HD * NC; i += 256) sW[i] = W2[i];
    if (t < HD) sb[t] = b1[t];
    if (t < NC) { sas[t] = att_s2[t]; sad[t] = att_d2[t]; }
    __syncthreads();
    int n = blockIdx.x * 256 + t;
    if (n >= N) return;
    const float* ag = agg1 + (size_t)n * HD;
    float* eo = emb_out + (size_t)n * HD;
    float acc[NC];
    #pragma unroll
    for (int c = 0; c < NC; ++c) acc[c] = 0.f;
    #pragma unroll 8
    for (int k = 0; k < HD; ++k) {
        float v = ag[k] + sb[k];
        eo[k] = v;
        float xv = v > 0.f ? v : expm1f(v);   // jax.nn.elu
        #pragma unroll
        for (int c = 0; c < NC; ++c) acc[c] += xv * sW[k * NC + c];
    }
    float as = 0.f, ad = 0.f;
    float* hp = h2p + (size_t)n * 8;
    #pragma unroll
    for (int c = 0; c < NC; ++c) {
        hp[c] = acc[c];
        as += acc[c] * sas[c];
        ad += acc[c] * sad[c];
    }
    hp[7] = 0.f;
    a_src2[n] = as;
    a_dst2[n] = ad;
}

// ------- K-gather2: WAVE per dst; depth-2 pipeline; fixed-CAP rows -----------
__global__ __launch_bounds__(256) void k_gather2(
    const int* __restrict__ cnt, const int* __restrict__ csrF,
    const int* __restrict__ ovfn, const int* __restrict__ ovf,
    const float* __restrict__ h2p, const float* __restrict__ a_src2,
    const float* __restrict__ a_dst2, const float* __restrict__ b2,
    float* __restrict__ out, int N)
{
    int t = threadIdx.x;
    int wave = t >> 6, lane = t & 63;
    int g = lane >> 3;           // edge slot 0..7
    int c = lane & 7;            // channel (7 = pad)
    int n = blockIdx.x * 4 + wave;
    if (n >= N) return;
    float ad = a_dst2[n];
    float w = __expf(lrelu(a_src2[n] + ad));   // self-loop
    float acc  = (g == 0) ? w * h2p[(size_t)n * 8 + c] : 0.f;
    float wsum = (g == 0) ? w : 0.f;

    int m = cnt[n]; if (m > CAP) m = CAP;
    int jb = n * CAP, je = jb + m;

    int  idx0 = jb + g;
    bool v0   = idx0 < je;
    int  s0   = v0 ? csrF[idx0] : n;
    float as0 = a_src2[s0];
    float hv0 = h2p[(size_t)s0 * 8 + c];

    int  idx1 = jb + 8 + g;
    bool v1   = idx1 < je;
    int  s1   = v1 ? csrF[idx1] : n;

    for (int j = jb; j < je; j += 8) {
        int  idx2 = j + 16 + g;
        bool v2   = idx2 < je;
        int  s2   = v2 ? csrF[idx2] : n;
        float as1 = a_src2[s1];
        float hv1 = h2p[(size_t)s1 * 8 + c];
        float ww = v0 ? __expf(lrelu(as0 + ad)) : 0.f;
        acc += ww * hv0;
        wsum += ww;
        v0 = v1; as0 = as1; hv0 = hv1;
        v1 = v2; s1 = s2;
    }

    // overflow entries (expected none)
    int no = *ovfn;
    if (no > 0) {
        if (no > OVF_CAP) no = OVF_CAP;
        for (int k2 = 0; k2 < no; ++k2) {
            int od = ovf[2 * k2], os = ovf[2 * k2 + 1];
            if (od == n && g == 0) {
                float ww = __expf(lrelu(a_src2[os] + ad));
                acc += ww * h2p[(size_t)os * 8 + c];
                wsum += ww;
            }
        }
    }

    #pragma unroll
    for (int o = 32; o >= 8; o >>= 1) {
        acc  += __shfl_xor(acc, o, 64);
        wsum += __shfl_xor(wsum, o, 64);
    }
    float l = (c < NC) ? (acc / (wsum + 1e-16f) + b2[c]) : -1e30f;
    float m2 = l;
    #pragma unroll
    for (int o = 4; o > 0; o >>= 1) m2 = fmaxf(m2, __shfl_xor(m2, o, 8));
    float ex = (c < NC) ? __expf(l - m2) : 0.f;
    float s8 = ex;
    #pragma unroll
    for (int o = 4; o > 0; o >>= 1) s8 += __shfl_xor(s8, o, 8);
    if (g == 0 && c < NC) out[(size_t)n * NC + c] = l - m2 - logf(s8);
}

extern "C" void kernel_launch(void* const* d_in, const int* in_sizes, int n_in,
                              void* d_out, int out_size, void* d_ws, size_t ws_size,
                              hipStream_t stream)
{
    const float* x       = (const float*)d_in[0];
    const int*   ei      = (const int*)d_in[1];
    const float* W1      = (const float*)d_in[2];
    const float* att_s1  = (const float*)d_in[3];
    const float* att_d1  = (const float*)d_in[4];
    const float* b1      = (const float*)d_in[5];
    const float* W2      = (const float*)d_in[6];
    const float* att_s2  = (const float*)d_in[7];
    const float* att_d2  = (const float*)d_in[8];
    const float* b2      = (const float*)d_in[9];

    const int  N = in_sizes[0] / F_IN;
    const long E = (long)in_sizes[1] / 2;
    const int* src = ei;
    const int* dst = ei + E;

    const int Npad  = (N + 3) & ~3;

    // ---- workspace layout ----
    int* cnt  = (int*)d_ws;                    // Npad   (zeroed)
    int* ovfn = cnt + Npad;                    // 8 (1 used, zeroed)
    int* ovf  = ovfn + 8;                      // 2*OVF_CAP
    int* csrF = ovf + 2 * OVF_CAP;             // N*CAP
    ushort* h1b   = (ushort*)(csrF + (size_t)N * CAP);  // Npad*64 bf16
    float* a_src1 = (float*)(h1b + (size_t)Npad * HD);  // N*8
    float* a_dst1 = a_src1 + (size_t)N * NH;   // N*8
    float* agg1   = a_dst1 + (size_t)N * NH;   // N*64
    float* h2p    = agg1 + (size_t)N * HD;     // N*8 (padded NC->8)
    float* a_src2 = h2p + (size_t)N * 8;       // Npad
    float* a_dst2 = a_src2 + Npad;             // Npad
    // W1 hi/lo frag buffers alias a_src2 block (written by k_wcvt before gemm,
    // dead before k_node2 writes a_src2; 16K ushorts << Npad*4B)
    ushort* Wh = (ushort*)a_src2;              // 8192 ushort
    ushort* Wl = Wh + 8192;                    // 8192 ushort

    hipMemsetAsync(cnt, 0, (size_t)(Npad + 8) * sizeof(int), stream);

    const int NB = (N + 255) / 256;
    const int GB = (N + 63) / 64;
    dim3 b256(256);

    // W1 -> bf16 hi/lo fragments
    k_wcvt<<<dim3(1), b256, 0, stream>>>(W1, Wh, Wl);

    // fused MFMA node transform + one-pass CSR scatter (independent work)
    k_gemm1h<<<dim3(3 * GB), b256, 0, stream>>>(
        x, Wh, Wl, att_s1, att_d1, h1b, a_src1, a_dst1, N, GB,
        src, dst, cnt, csrF, ovfn, ovf, E);

    // Layer 1 aggregate
    k_gather1<<<dim3((N + 3) / 4), b256, 0, stream>>>(
        cnt, csrF, ovfn, ovf, h1b, a_src1, a_dst1, agg1, N);

    // emb output + layer-2 prologue
    float* emb = (float*)d_out;               // N*64
    float* lsm = emb + (size_t)N * HD;        // N*7
    k_node2<<<dim3(NB), b256, 0, stream>>>(
        agg1, b1, W2, att_s2, att_d2, emb, h2p, a_src2, a_dst2, N);

    // Layer 2 aggregate + fused log_softmax
    k_gather2<<<dim3((N + 3) / 4), b256, 0, stream>>>(
        cnt, csrF, ovfn, ovf, h2p, a_src2, a_dst2, b2, lsm, N);
}